// Round 6
// baseline (325.530 us; speedup 1.0000x reference)
//
#include <hip/hip_runtime.h>
#include <math.h>

// Problem constants (from reference setup_inputs)
#define Bb 8
#define Cc 24
#define Hh 320
#define Ww 640
#define HWp (Hh * Ww)        // 204800
#define NPIX (Bb * HWp)      // 1638400
#define BLK 512
#define GRP 2                // float4 groups per thread -> 8 px/thread
#define TILE (BLK * GRP * 4) // 4096 px per block -> 16 KB per plane-visit

// v7: run-length experiment. Falsified so far: per-wave MLP (v4: guaranteed
// 24 async loads in flight, no change), VGPR/occupancy (20/36/56 regs,
// 35-55% occ, all identical), disparity gather (v6: dv-carry, no change).
// v6's decisive clue: logical delivery hit 2.7 TB/s (300MB in 118us, half
// L3-retained) while HBM fetch pinned at 1.5 TB/s -> the floor is the HBM
// fetch path for THIS pattern. Distinguishing feature vs a 6.3 TB/s copy:
// 4KB runs per plane-visit, thousands of interleaved short bursts at the
// controllers. This version makes each block's plane-visit a 16KB
// contiguous run (512 thr x 8 px x 4B), 4x v6, with v6's proven dv-carry
// math (bit-identical selects). State 32 scalars/thread -> no spill risk
// (v5's confound). Grid 400 x 8 waves = 12.5 waves/CU.
__global__ __launch_bounds__(BLK) void sparse_regression_kernel(
    const float* __restrict__ cost,
    const float* __restrict__ disp,
    float* __restrict__ pred,   // [B,H,W]   = NPIX floats
    float* __restrict__ prob)   // [B,2,H,W] = 2*NPIX floats
{
    const int lane = threadIdx.x & 63;
    const int wid  = threadIdx.x >> 6;          // 0..7
    const int tq   = blockIdx.x * TILE;         // tile base pixel (global)
    const int b    = tq / HWp;                  // HWp % TILE == 0 -> no straddle
    // group g of this thread covers pixels q0 + g*256 .. +3 (lane-contiguous
    // 1KB per instr; 16 chunks of 1KB tile the 16KB plane-visit run)
    const int q0   = (tq - b * HWp) + wid * (GRP * 256) + lane * 4;

    const size_t base  = (size_t)b * Cc * HWp + q0;
    const float* cb    = cost + base;
    const float* db    = disp + base;

    float m1[GRP][4], m2[GRP][4], dv1[GRP][4], dv2[GRP][4];
#pragma unroll
    for (int g = 0; g < GRP; ++g)
#pragma unroll
        for (int k = 0; k < 4; ++k) {
            m1[g][k] = -INFINITY; m2[g][k] = -INFINITY;
            dv1[g][k] = 0.0f;     dv2[g][k] = 0.0f;
        }

    // Plane-major sweep: per channel, the block reads 16KB contiguous from
    // the cost plane and 16KB from the disp plane. Strict '>' scanning c
    // ascending reproduces lax.top_k's lower-index-wins tie-breaking
    // (same select booleans as v1/v6).
#pragma unroll
    for (int c = 0; c < Cc; ++c) {
        float4 cv[GRP], dvv[GRP];
#pragma unroll
        for (int g = 0; g < GRP; ++g) {
            cv[g]  = *(const float4*)(cb + (size_t)c * HWp + g * 256);
            dvv[g] = *(const float4*)(db + (size_t)c * HWp + g * 256);
        }
#pragma unroll
        for (int g = 0; g < GRP; ++g) {
            const float cc[4] = {cv[g].x,  cv[g].y,  cv[g].z,  cv[g].w};
            const float dd[4] = {dvv[g].x, dvv[g].y, dvv[g].z, dvv[g].w};
#pragma unroll
            for (int k = 0; k < 4; ++k) {
                const float val = cc[k];
                const float dvl = dd[k];
                const bool gt1 = val > m1[g][k];
                const bool gt2 = val > m2[g][k];
                m2[g][k]  = gt1 ? m1[g][k]  : (gt2 ? val : m2[g][k]);
                dv2[g][k] = gt1 ? dv1[g][k] : (gt2 ? dvl : dv2[g][k]);
                m1[g][k]  = gt1 ? val       : m1[g][k];
                dv1[g][k] = gt1 ? dvl       : dv1[g][k];
            }
        }
    }

    // Epilogue + coalesced float4 stores.
#pragma unroll
    for (int g = 0; g < GRP; ++g) {
        float predo[4], p1o[4], p2o[4];
#pragma unroll
        for (int k = 0; k < 4; ++k) {
            // softmax over {m1, m2}: p1 = 1/(1+exp(m2-m1)), m2-m1 <= 0
            const float e  = __expf(m2[g][k] - m1[g][k]);
            const float p1 = 1.0f / (1.0f + e);
            const float p2 = 1.0f - p1;
            predo[k] = dv1[g][k] * p1 + dv2[g][k] * p2;
            p1o[k] = p1;
            p2o[k] = p2;
        }
        const int q = q0 + g * 256;                  // within-batch pixel
        *(float4*)(pred + (size_t)b * HWp + q) =
            make_float4(predo[0], predo[1], predo[2], predo[3]);
        float* pb = prob + (size_t)b * 2 * HWp + q;
        *(float4*)(pb)       = make_float4(p1o[0], p1o[1], p1o[2], p1o[3]);
        *(float4*)(pb + HWp) = make_float4(p2o[0], p2o[1], p2o[2], p2o[3]);
    }
}

extern "C" void kernel_launch(void* const* d_in, const int* in_sizes, int n_in,
                              void* d_out, int out_size, void* d_ws, size_t ws_size,
                              hipStream_t stream) {
    const float* cost = (const float*)d_in[0];
    const float* disp = (const float*)d_in[1];
    float* pred = (float*)d_out;          // first NPIX floats
    float* prob = (float*)d_out + NPIX;   // next 2*NPIX floats

    const int grid = NPIX / TILE;         // 400, exact
    sparse_regression_kernel<<<grid, BLK, 0, stream>>>(cost, disp, pred, prob);
}

// Round 8
// 313.525 us; speedup vs baseline: 1.0383x; 1.0383x over previous
//
#include <hip/hip_runtime.h>
#include <math.h>

// Problem constants (from reference setup_inputs)
#define Bb 8
#define Cc 24
#define Hh 320
#define Ww 640
#define HWp (Hh * Ww)        // 204800
#define NPIX (Bb * HWp)      // 1638400
#define PIX_PER_THREAD 4

// Native clang vector type: __builtin_nontemporal_load/store require a
// pointer to scalar-or-vector-of-scalar, not HIP's struct vector types.
typedef float f4 __attribute__((ext_vector_type(4)));

// v8b: L3-churn experiment (v8 had a compile error only; theory unchanged).
// Falsified: per-wave MLP (v4 async queue), occ/VGPR (26-55%, 20-64 regs:
// identical), disparity gather (v6 dv-carry), run length (v7 16KB/visit),
// logical volume (v6 2x: free). Invariant: HBM fetch path delivers ~150MB
// cold lines/dispatch at ~1.3-1.5 TB/s while the CU-side hierarchy proved
// 2.7 TB/s delivery (v6). Theory: working set (333MB) > L3 (256MB) ->
// cyclic thrash; every miss costs an L3 allocate+victim and THAT path is
// the fixed-rate throat. Fix: nt-load the cost stream (no L3 alloc) + nt
// stores; disp (157MB) then fits L3 entirely -> ~0 churn.
// Math/selects identical to v6 (dv-carry, strict '>' ascending).
__global__ __launch_bounds__(256) void sparse_regression_kernel(
    const float* __restrict__ cost,
    const float* __restrict__ disp,
    float* __restrict__ pred,   // [B,H,W]   = NPIX floats
    float* __restrict__ prob)   // [B,2,H,W] = 2*NPIX floats
{
    const int t  = blockIdx.x * blockDim.x + threadIdx.x;
    const int p0 = t * PIX_PER_THREAD;
    if (p0 >= NPIX) return;

    const int b = p0 / HWp;          // 4-pixel groups never straddle b (HW%4==0)
    const int q = p0 - b * HWp;      // h*W + w

    const size_t base = (size_t)b * Cc * HWp + q;
    const float* cbase = cost + base;
    const float* dbase = disp + base;

    float m1[PIX_PER_THREAD], m2[PIX_PER_THREAD];
    float dv1[PIX_PER_THREAD], dv2[PIX_PER_THREAD];
#pragma unroll
    for (int j = 0; j < PIX_PER_THREAD; ++j) {
        m1[j] = -INFINITY; m2[j] = -INFINITY;
        dv1[j] = 0.0f;     dv2[j] = 0.0f;
    }

    // Streaming top-2 over channels, carrying disparity values.
    // cost: non-temporal (bypass cache allocation). disp: cached (L3-resident).
#pragma unroll
    for (int c = 0; c < Cc; ++c) {
        const f4 cv = __builtin_nontemporal_load(
            (const f4*)(cbase + (size_t)c * HWp));
        const f4 dv = *(const f4*)(dbase + (size_t)c * HWp);
#pragma unroll
        for (int j = 0; j < PIX_PER_THREAD; ++j) {
            const float val = cv[j];
            const float dvl = dv[j];
            const bool gt1 = val > m1[j];
            const bool gt2 = val > m2[j];
            m2[j]  = gt1 ? m1[j]  : (gt2 ? val : m2[j]);
            dv2[j] = gt1 ? dv1[j] : (gt2 ? dvl : dv2[j]);
            m1[j]  = gt1 ? val    : m1[j];
            dv1[j] = gt1 ? dvl    : dv1[j];
        }
    }

    f4 predo, p1o, p2o;
#pragma unroll
    for (int j = 0; j < PIX_PER_THREAD; ++j) {
        // softmax over {m1, m2}: p1 = 1/(1+exp(m2-m1)), m2-m1 <= 0
        const float e  = __expf(m2[j] - m1[j]);
        const float p1 = 1.0f / (1.0f + e);
        const float p2 = 1.0f - p1;
        predo[j] = dv1[j] * p1 + dv2[j] * p2;
        p1o[j] = p1;
        p2o[j] = p2;
    }

    // Coalesced non-temporal float4 stores (outputs are never re-read here).
    __builtin_nontemporal_store(predo, (f4*)(pred + p0));
    float* pb = prob + (size_t)b * 2 * HWp + q;
    __builtin_nontemporal_store(p1o, (f4*)(pb));
    __builtin_nontemporal_store(p2o, (f4*)(pb + HWp));
}

extern "C" void kernel_launch(void* const* d_in, const int* in_sizes, int n_in,
                              void* d_out, int out_size, void* d_ws, size_t ws_size,
                              hipStream_t stream) {
    const float* cost = (const float*)d_in[0];
    const float* disp = (const float*)d_in[1];
    float* pred = (float*)d_out;          // first NPIX floats
    float* prob = (float*)d_out + NPIX;   // next 2*NPIX floats

    const int threads = NPIX / PIX_PER_THREAD;   // 409600
    const int block = 256;
    const int grid = (threads + block - 1) / block;  // 1600
    sparse_regression_kernel<<<grid, block, 0, stream>>>(cost, disp, pred, prob);
}